// Round 1
// baseline (202.951 us; speedup 1.0000x reference)
//
#include <hip/hip_runtime.h>
#include <hip/hip_bf16.h>

// Problem constants (match reference)
#define T_TOK 8192
#define DDIM  1024
#define HDIM  512
#define NE    8
#define TPE   (T_TOK / NE)   // 1024 tokens per expert (static partition per reference)

typedef __attribute__((ext_vector_type(4))) float floatx4;
typedef __attribute__((ext_vector_type(8))) short bf16x8;

__device__ __forceinline__ unsigned short f2bf(float f) {
    union { float f; unsigned int u; } v;
    v.f = f;
    unsigned int u = v.u;
    unsigned int r = u + 0x7FFFu + ((u >> 16) & 1u);  // RNE
    return (unsigned short)(r >> 16);
}

// ---------------------------------------------------------------------------
// Kernel 1: h = silu(X W1^T) * (X W3^T), fused dequant (x * scale -> bf16).
// C = A * B^T. Tile 128 (tokens) x 128 (h cols), BK=64, 4 waves of 64x64.
// Per block: two accumulator sets (h1 against w13 rows [n,n+128),
//            h3 against w13 rows [H+n, H+n+128)).
// grid = 8 experts * 8 token-tiles * 4 h-tiles = 256 blocks, 256 threads.
// ---------------------------------------------------------------------------
__global__ __launch_bounds__(256, 2)
void gemm1_silu_kernel(const float* __restrict__ X,
                       const float* __restrict__ S,
                       const float* __restrict__ W13,
                       __hip_bfloat16* __restrict__ Hout)
{
    const int bid = blockIdx.x;
    const int e  = bid >> 5;          // /32
    const int mt = (bid >> 2) & 7;    // token tile
    const int nt = bid & 3;           // h tile
    const int tok0 = e * TPE + mt * 128;
    const float* __restrict__ We = W13 + (size_t)e * (2 * HDIM) * DDIM;

    __shared__ __hip_bfloat16 sA [128][64];
    __shared__ __hip_bfloat16 sB1[128][64];
    __shared__ __hip_bfloat16 sB3[128][64];

    const int tid  = threadIdx.x;
    const int lane = tid & 63;
    const int wave = tid >> 6;
    const int wr = wave >> 1;   // 0..1
    const int wc = wave & 1;    // 0..1
    const int lr = lane & 15;             // fragment row/col
    const int lk = (lane >> 4) * 8;       // fragment k base

    floatx4 acc1[4][4] = {};
    floatx4 acc3[4][4] = {};

    for (int kk = 0; kk < DDIM / 64; ++kk) {
        const int k0 = kk * 64;
        __syncthreads();   // protect LDS from previous iteration's readers
        // ---- stage A: X * scale -> bf16, 128x64 elems, float4 granularity
        #pragma unroll
        for (int i = 0; i < 8; ++i) {
            int idx = tid + i * 256;          // 0..2047
            int row = idx >> 4;
            int col = (idx & 15) * 4;
            const float4 v = *reinterpret_cast<const float4*>(
                &X[(size_t)(tok0 + row) * DDIM + k0 + col]);
            float sc = S[(size_t)(tok0 + row) * (DDIM / 32) + ((k0 + col) >> 5)];
            ushort4 b;
            b.x = f2bf(v.x * sc); b.y = f2bf(v.y * sc);
            b.z = f2bf(v.z * sc); b.w = f2bf(v.w * sc);
            *reinterpret_cast<ushort4*>(&sA[row][col]) = b;
        }
        // ---- stage B1 (w1 rows) and B3 (w3 rows): fp32 -> bf16
        #pragma unroll
        for (int i = 0; i < 8; ++i) {
            int idx = tid + i * 256;
            int row = idx >> 4;
            int col = (idx & 15) * 4;
            const float4 v1 = *reinterpret_cast<const float4*>(
                &We[(size_t)(nt * 128 + row) * DDIM + k0 + col]);
            ushort4 b1;
            b1.x = f2bf(v1.x); b1.y = f2bf(v1.y); b1.z = f2bf(v1.z); b1.w = f2bf(v1.w);
            *reinterpret_cast<ushort4*>(&sB1[row][col]) = b1;
            const float4 v3 = *reinterpret_cast<const float4*>(
                &We[(size_t)(HDIM + nt * 128 + row) * DDIM + k0 + col]);
            ushort4 b3;
            b3.x = f2bf(v3.x); b3.y = f2bf(v3.y); b3.z = f2bf(v3.z); b3.w = f2bf(v3.w);
            *reinterpret_cast<ushort4*>(&sB3[row][col]) = b3;
        }
        __syncthreads();
        // ---- compute: 2 k-sub x 4x4 fragments x 2 (h1,h3)
        #pragma unroll
        for (int ks = 0; ks < 2; ++ks) {
            bf16x8 a[4], b1[4], b3[4];
            #pragma unroll
            for (int m = 0; m < 4; ++m)
                a[m] = *reinterpret_cast<const bf16x8*>(&sA[wr * 64 + m * 16 + lr][ks * 32 + lk]);
            #pragma unroll
            for (int n = 0; n < 4; ++n) {
                b1[n] = *reinterpret_cast<const bf16x8*>(&sB1[wc * 64 + n * 16 + lr][ks * 32 + lk]);
                b3[n] = *reinterpret_cast<const bf16x8*>(&sB3[wc * 64 + n * 16 + lr][ks * 32 + lk]);
            }
            #pragma unroll
            for (int m = 0; m < 4; ++m)
                #pragma unroll
                for (int n = 0; n < 4; ++n) {
                    acc1[m][n] = __builtin_amdgcn_mfma_f32_16x16x32_bf16(a[m], b1[n], acc1[m][n], 0, 0, 0);
                    acc3[m][n] = __builtin_amdgcn_mfma_f32_16x16x32_bf16(a[m], b3[n], acc3[m][n], 0, 0, 0);
                }
        }
    }

    // ---- epilogue: h = silu(h1) * h3 -> bf16
    // C/D layout: col = lane&15, row = (lane>>4)*4 + i   [measured m89/m91]
    const int hcol0 = nt * 128 + wc * 64;
    #pragma unroll
    for (int m = 0; m < 4; ++m) {
        #pragma unroll
        for (int n = 0; n < 4; ++n) {
            #pragma unroll
            for (int i = 0; i < 4; ++i) {
                int row = tok0 + wr * 64 + m * 16 + (lane >> 4) * 4 + i;
                int col = hcol0 + n * 16 + (lane & 15);
                float h1 = acc1[m][n][i];
                float h3 = acc3[m][n][i];
                float sig = 1.0f / (1.0f + __expf(-h1));
                float hv = h1 * sig * h3;
                Hout[(size_t)row * HDIM + col] = __float2bfloat16(hv);
            }
        }
    }
}

// ---------------------------------------------------------------------------
// Kernel 2: out = h W2^T.  A = h (bf16, ws), B = w2 (fp32 -> bf16), C fp32.
// Tile 128x128, BK=64, K=512. grid = 8 * 8 token-tiles * 8 d-tiles = 512.
// ---------------------------------------------------------------------------
__global__ __launch_bounds__(256, 2)
void gemm2_kernel(const __hip_bfloat16* __restrict__ Hin,
                  const float* __restrict__ W2,
                  float* __restrict__ Out)
{
    const int bid = blockIdx.x;
    const int e  = bid >> 6;          // /64
    const int mt = (bid >> 3) & 7;    // token tile
    const int nt = bid & 7;           // d tile
    const int tok0 = e * TPE + mt * 128;
    const float* __restrict__ We = W2 + (size_t)e * DDIM * HDIM;

    __shared__ __hip_bfloat16 sA[128][64];
    __shared__ __hip_bfloat16 sB[128][64];

    const int tid  = threadIdx.x;
    const int lane = tid & 63;
    const int wave = tid >> 6;
    const int wr = wave >> 1;
    const int wc = wave & 1;
    const int lr = lane & 15;
    const int lk = (lane >> 4) * 8;

    floatx4 acc[4][4] = {};

    for (int kk = 0; kk < HDIM / 64; ++kk) {
        const int k0 = kk * 64;
        __syncthreads();
        // ---- stage A (already bf16): 16B = 8 elems per load, 1024 loads
        #pragma unroll
        for (int i = 0; i < 4; ++i) {
            int idx = tid + i * 256;          // 0..1023
            int row = idx >> 3;
            int col = (idx & 7) * 8;
            uint4 v = *reinterpret_cast<const uint4*>(
                &Hin[(size_t)(tok0 + row) * HDIM + k0 + col]);
            *reinterpret_cast<uint4*>(&sA[row][col]) = v;
        }
        // ---- stage B: w2 rows (d), fp32 -> bf16
        #pragma unroll
        for (int i = 0; i < 8; ++i) {
            int idx = tid + i * 256;
            int row = idx >> 4;
            int col = (idx & 15) * 4;
            const float4 v = *reinterpret_cast<const float4*>(
                &We[(size_t)(nt * 128 + row) * HDIM + k0 + col]);
            ushort4 b;
            b.x = f2bf(v.x); b.y = f2bf(v.y); b.z = f2bf(v.z); b.w = f2bf(v.w);
            *reinterpret_cast<ushort4*>(&sB[row][col]) = b;
        }
        __syncthreads();
        #pragma unroll
        for (int ks = 0; ks < 2; ++ks) {
            bf16x8 a[4], b[4];
            #pragma unroll
            for (int m = 0; m < 4; ++m)
                a[m] = *reinterpret_cast<const bf16x8*>(&sA[wr * 64 + m * 16 + lr][ks * 32 + lk]);
            #pragma unroll
            for (int n = 0; n < 4; ++n)
                b[n] = *reinterpret_cast<const bf16x8*>(&sB[wc * 64 + n * 16 + lr][ks * 32 + lk]);
            #pragma unroll
            for (int m = 0; m < 4; ++m)
                #pragma unroll
                for (int n = 0; n < 4; ++n)
                    acc[m][n] = __builtin_amdgcn_mfma_f32_16x16x32_bf16(a[m], b[n], acc[m][n], 0, 0, 0);
        }
    }

    const int dcol0 = nt * 128 + wc * 64;
    #pragma unroll
    for (int m = 0; m < 4; ++m) {
        #pragma unroll
        for (int n = 0; n < 4; ++n) {
            #pragma unroll
            for (int i = 0; i < 4; ++i) {
                int row = tok0 + wr * 64 + m * 16 + (lane >> 4) * 4 + i;
                int col = dcol0 + n * 16 + (lane & 15);
                Out[(size_t)row * DDIM + col] = acc[m][n][i];
            }
        }
    }
}

extern "C" void kernel_launch(void* const* d_in, const int* in_sizes, int n_in,
                              void* d_out, int out_size, void* d_ws, size_t ws_size,
                              hipStream_t stream) {
    const float* X   = (const float*)d_in[0];   // (T, D) fp32
    const float* S   = (const float*)d_in[1];   // (T, D/32) fp32
    // d_in[2] num_tokens_per_expert, d_in[3] expert_padded_offsets: unused by reference
    const float* W13 = (const float*)d_in[4];   // (E, 2H, D) fp32
    const float* W2  = (const float*)d_in[5];   // (E, D, H) fp32
    float* Out = (float*)d_out;                 // (T, D) fp32
    __hip_bfloat16* Hbuf = (__hip_bfloat16*)d_ws;  // (T, H) bf16 = 8 MB scratch

    gemm1_silu_kernel<<<NE * 8 * 4, 256, 0, stream>>>(X, S, W13, Hbuf);
    gemm2_kernel<<<NE * 8 * 8, 256, 0, stream>>>(Hbuf, W2, Out);
}

// Round 2
// 113.032 us; speedup vs baseline: 1.7955x; 1.7955x over previous
//
#include <hip/hip_runtime.h>
#include <hip/hip_bf16.h>

// Problem constants (match reference)
#define T_TOK 8192
#define DDIM  1024
#define HDIM  512
#define NE    8
#define TPE   (T_TOK / NE)   // 1024 tokens per expert (static partition per reference)

typedef __attribute__((ext_vector_type(4))) float floatx4;
typedef __attribute__((ext_vector_type(8))) short bf16x8;

__device__ __forceinline__ unsigned short f2bf(float f) {
    union { float f; unsigned int u; } v;
    v.f = f;
    unsigned int u = v.u;
    unsigned int r = u + 0x7FFFu + ((u >> 16) & 1u);  // RNE
    return (unsigned short)(r >> 16);
}

// async global -> LDS, 16 bytes per lane (dest must be linear: base + lane*16)
__device__ __forceinline__ void gld_lds16(const void* g, void* l) {
    __builtin_amdgcn_global_load_lds(
        (const __attribute__((address_space(1))) unsigned int*)g,
        (__attribute__((address_space(3))) unsigned int*)l, 16, 0, 0);
}

// ---------------------------------------------------------------------------
// Kernel 0: convert W13 and W2 fp32 -> bf16 into workspace (streaming).
// ---------------------------------------------------------------------------
__global__ __launch_bounds__(256)
void convert_w_kernel(const float* __restrict__ W13, const float* __restrict__ W2,
                      unsigned short* __restrict__ W13b, unsigned short* __restrict__ W2b)
{
    const int NT13 = (NE * 2 * HDIM * DDIM) / 4;   // float4 count: 2,097,152
    const int NT2  = (NE * DDIM * HDIM) / 4;       // float4 count: 1,048,576
    const int stride = gridDim.x * blockDim.x;
    for (int i = blockIdx.x * blockDim.x + threadIdx.x; i < NT13 + NT2; i += stride) {
        const float4* src;
        ushort4* dst;
        int j;
        if (i < NT13) { src = (const float4*)W13; dst = (ushort4*)W13b; j = i; }
        else          { src = (const float4*)W2;  dst = (ushort4*)W2b;  j = i - NT13; }
        float4 v = src[j];
        ushort4 b;
        b.x = f2bf(v.x); b.y = f2bf(v.y); b.z = f2bf(v.z); b.w = f2bf(v.w);
        dst[j] = b;
    }
}

// ---------------------------------------------------------------------------
// Kernel 1: h = silu(X W1^T) * (X W3^T), dequant fused into A-staging.
// Tile: M=128 tokens x N=64 h-cols, BK=64.
// A reg-staged (fp32 * scale -> bf16); B1/B3 via global_load_lds (bf16).
// 4 waves (2x2); per-wave 64x32 per set. grid = 8e * 8mt * 8nt = 512 blocks.
// LDS = 16 + 8 + 8 = 32 KB -> 2+ blocks/CU.
// ---------------------------------------------------------------------------
__global__ __launch_bounds__(256, 2)
void gemm1_silu_kernel(const float* __restrict__ X,
                       const float* __restrict__ S,
                       const unsigned short* __restrict__ W13b,
                       __hip_bfloat16* __restrict__ Hout)
{
    const int bid = blockIdx.x;
    const int e  = bid >> 6;          // /64
    const int mt = (bid >> 3) & 7;    // token tile (128 rows)
    const int nt = bid & 7;           // h tile (64 cols)
    const int tok0 = e * TPE + mt * 128;
    const unsigned short* __restrict__ We = W13b + (size_t)e * (2 * HDIM) * DDIM;

    __shared__ __hip_bfloat16 sA [128][64];
    __shared__ __hip_bfloat16 sB1[64][64];
    __shared__ __hip_bfloat16 sB3[64][64];

    const int tid  = threadIdx.x;
    const int lane = tid & 63;
    const int wave = tid >> 6;
    const int wr = wave >> 1;   // 0..1 (M)
    const int wc = wave & 1;    // 0..1 (N: 32 each)
    const int lr = lane & 15;
    const int lk = (lane >> 4) * 8;

    floatx4 acc1[4][2] = {};
    floatx4 acc3[4][2] = {};

    // B staging geometry: chunk c in [0,512): row = c>>3, col = (c&7)*8 elems
    const int brow0 = (tid >> 3);         // chunk j=0 row (c = tid)
    const int bcol  = (tid & 7) * 8;

    for (int kk = 0; kk < DDIM / 64; ++kk) {
        const int k0 = kk * 64;
        // ---- issue async B loads first (fly under A-staging)
        #pragma unroll
        for (int j = 0; j < 2; ++j) {
            int row = brow0 + j * 32;     // +256 chunks = +32 rows
            gld_lds16(&We[(size_t)(nt * 64 + row) * DDIM + k0 + bcol],
                      &sB1[row][bcol]);
            gld_lds16(&We[(size_t)(HDIM + nt * 64 + row) * DDIM + k0 + bcol],
                      &sB3[row][bcol]);
        }
        // ---- stage A: X * scale -> bf16, 128x64 elems
        #pragma unroll
        for (int i = 0; i < 8; ++i) {
            int idx = tid + i * 256;          // 0..2047
            int row = idx >> 4;
            int col = (idx & 15) * 4;
            const float4 v = *reinterpret_cast<const float4*>(
                &X[(size_t)(tok0 + row) * DDIM + k0 + col]);
            float sc = S[(size_t)(tok0 + row) * (DDIM / 32) + ((k0 + col) >> 5)];
            ushort4 b;
            b.x = f2bf(v.x * sc); b.y = f2bf(v.y * sc);
            b.z = f2bf(v.z * sc); b.w = f2bf(v.w * sc);
            *reinterpret_cast<ushort4*>(&sA[row][col]) = b;
        }
        __syncthreads();   // drains vmcnt (async B) + lgkm (A writes)
        // ---- compute
        #pragma unroll
        for (int ks = 0; ks < 2; ++ks) {
            bf16x8 a[4], b1[2], b3[2];
            #pragma unroll
            for (int m = 0; m < 4; ++m)
                a[m] = *reinterpret_cast<const bf16x8*>(&sA[wr * 64 + m * 16 + lr][ks * 32 + lk]);
            #pragma unroll
            for (int n = 0; n < 2; ++n) {
                b1[n] = *reinterpret_cast<const bf16x8*>(&sB1[wc * 32 + n * 16 + lr][ks * 32 + lk]);
                b3[n] = *reinterpret_cast<const bf16x8*>(&sB3[wc * 32 + n * 16 + lr][ks * 32 + lk]);
            }
            #pragma unroll
            for (int m = 0; m < 4; ++m)
                #pragma unroll
                for (int n = 0; n < 2; ++n) {
                    acc1[m][n] = __builtin_amdgcn_mfma_f32_16x16x32_bf16(a[m], b1[n], acc1[m][n], 0, 0, 0);
                    acc3[m][n] = __builtin_amdgcn_mfma_f32_16x16x32_bf16(a[m], b3[n], acc3[m][n], 0, 0, 0);
                }
        }
        __syncthreads();   // protect LDS before next stage
    }

    // ---- epilogue: h = silu(h1) * h3 -> bf16
    // C/D layout: col = lane&15, row = (lane>>4)*4 + i
    const int hcol0 = nt * 64 + wc * 32;
    #pragma unroll
    for (int m = 0; m < 4; ++m) {
        #pragma unroll
        for (int n = 0; n < 2; ++n) {
            #pragma unroll
            for (int i = 0; i < 4; ++i) {
                int row = tok0 + wr * 64 + m * 16 + (lane >> 4) * 4 + i;
                int col = hcol0 + n * 16 + (lane & 15);
                float h1 = acc1[m][n][i];
                float h3 = acc3[m][n][i];
                float sig = 1.0f / (1.0f + __expf(-h1));
                Hout[(size_t)row * HDIM + col] = __float2bfloat16(h1 * sig * h3);
            }
        }
    }
}

// ---------------------------------------------------------------------------
// Kernel 2: out = h W2^T. All-bf16, both operands via global_load_lds.
// Tile 128x128, BK=64, K=512. grid = 8e * 8mt * 8nt = 512 blocks.
// ---------------------------------------------------------------------------
__global__ __launch_bounds__(256, 2)
void gemm2_kernel(const __hip_bfloat16* __restrict__ Hin,
                  const unsigned short* __restrict__ W2b,
                  float* __restrict__ Out)
{
    const int bid = blockIdx.x;
    const int e  = bid >> 6;
    const int mt = (bid >> 3) & 7;
    const int nt = bid & 7;
    const int tok0 = e * TPE + mt * 128;
    const unsigned short* __restrict__ We = W2b + (size_t)e * DDIM * HDIM;

    __shared__ __hip_bfloat16 sA[128][64];
    __shared__ __hip_bfloat16 sB[128][64];

    const int tid  = threadIdx.x;
    const int lane = tid & 63;
    const int wave = tid >> 6;
    const int wr = wave >> 1;
    const int wc = wave & 1;
    const int lr = lane & 15;
    const int lk = (lane >> 4) * 8;

    floatx4 acc[4][4] = {};

    // staging geometry: chunk c in [0,1024): row = c>>3, col = (c&7)*8
    const int srow0 = (tid >> 3);
    const int scol  = (tid & 7) * 8;

    for (int kk = 0; kk < HDIM / 64; ++kk) {
        const int k0 = kk * 64;
        #pragma unroll
        for (int j = 0; j < 4; ++j) {
            int row = srow0 + j * 32;
            gld_lds16(&Hin[(size_t)(tok0 + row) * HDIM + k0 + scol],
                      &sA[row][scol]);
            gld_lds16(&We[(size_t)(nt * 128 + row) * HDIM + k0 + scol],
                      &sB[row][scol]);
        }
        __syncthreads();
        #pragma unroll
        for (int ks = 0; ks < 2; ++ks) {
            bf16x8 a[4], b[4];
            #pragma unroll
            for (int m = 0; m < 4; ++m)
                a[m] = *reinterpret_cast<const bf16x8*>(&sA[wr * 64 + m * 16 + lr][ks * 32 + lk]);
            #pragma unroll
            for (int n = 0; n < 4; ++n)
                b[n] = *reinterpret_cast<const bf16x8*>(&sB[wc * 64 + n * 16 + lr][ks * 32 + lk]);
            #pragma unroll
            for (int m = 0; m < 4; ++m)
                #pragma unroll
                for (int n = 0; n < 4; ++n)
                    acc[m][n] = __builtin_amdgcn_mfma_f32_16x16x32_bf16(a[m], b[n], acc[m][n], 0, 0, 0);
        }
        __syncthreads();
    }

    const int dcol0 = nt * 128 + wc * 64;
    #pragma unroll
    for (int m = 0; m < 4; ++m) {
        #pragma unroll
        for (int n = 0; n < 4; ++n) {
            #pragma unroll
            for (int i = 0; i < 4; ++i) {
                int row = tok0 + wr * 64 + m * 16 + (lane >> 4) * 4 + i;
                int col = dcol0 + n * 16 + (lane & 15);
                Out[(size_t)row * DDIM + col] = acc[m][n][i];
            }
        }
    }
}

extern "C" void kernel_launch(void* const* d_in, const int* in_sizes, int n_in,
                              void* d_out, int out_size, void* d_ws, size_t ws_size,
                              hipStream_t stream) {
    const float* X   = (const float*)d_in[0];   // (T, D) fp32
    const float* S   = (const float*)d_in[1];   // (T, D/32) fp32
    const float* W13 = (const float*)d_in[4];   // (E, 2H, D) fp32
    const float* W2  = (const float*)d_in[5];   // (E, D, H) fp32
    float* Out = (float*)d_out;                 // (T, D) fp32

    // workspace layout (bytes):
    //   [0, 16Mi)    W13b bf16 (E*2H*D)
    //   [16Mi, 24Mi) W2b  bf16 (E*D*H)
    //   [24Mi, 32Mi) Hb   bf16 (T*H)
    unsigned short* W13b = (unsigned short*)d_ws;
    unsigned short* W2b  = W13b + (size_t)NE * 2 * HDIM * DDIM;
    __hip_bfloat16* Hb   = (__hip_bfloat16*)(W2b + (size_t)NE * DDIM * HDIM);

    convert_w_kernel<<<2048, 256, 0, stream>>>(W13, W2, W13b, W2b);
    gemm1_silu_kernel<<<NE * 8 * 8, 256, 0, stream>>>(X, S, W13b, Hb);
    gemm2_kernel<<<NE * 8 * 8, 256, 0, stream>>>(Hb, W2b, (float*)Out);
}

// Round 3
// 69.138 us; speedup vs baseline: 2.9354x; 1.6349x over previous
//
#include <hip/hip_runtime.h>
#include <hip/hip_bf16.h>

// Problem constants (match reference)
#define T_TOK 8192
#define DDIM  1024
#define HDIM  512
#define NE    8
#define TPE   (T_TOK / NE)   // 1024 tokens per expert (static partition per reference)

typedef __attribute__((ext_vector_type(4))) float floatx4;
typedef __attribute__((ext_vector_type(8))) short bf16x8;

__device__ __forceinline__ unsigned short f2bf(float f) {
    union { float f; unsigned int u; } v;
    v.f = f;
    unsigned int u = v.u;
    unsigned int r = u + 0x7FFFu + ((u >> 16) & 1u);  // RNE
    return (unsigned short)(r >> 16);
}

// async global -> LDS, 16 bytes per lane (dest must be linear: base + lane*16)
__device__ __forceinline__ void gld_lds16(const void* g, void* l) {
    __builtin_amdgcn_global_load_lds(
        (const __attribute__((address_space(1))) unsigned int*)g,
        (__attribute__((address_space(3))) unsigned int*)l, 16, 0, 0);
}

// ---------------------------------------------------------------------------
// Kernel 0 (streaming): W13 fp32->bf16, W2 fp32->bf16, X*scale -> bf16.
// ---------------------------------------------------------------------------
__global__ __launch_bounds__(256)
void convert_kernel(const float* __restrict__ X, const float* __restrict__ S,
                    const float* __restrict__ W13, const float* __restrict__ W2,
                    unsigned short* __restrict__ Xb,
                    unsigned short* __restrict__ W13b,
                    unsigned short* __restrict__ W2b)
{
    const int NTX  = (T_TOK * DDIM) / 4;           // 2,097,152 float4 chunks
    const int NT13 = (NE * 2 * HDIM * DDIM) / 4;   // 2,097,152
    const int NT2  = (NE * DDIM * HDIM) / 4;       // 1,048,576
    const int stride = gridDim.x * blockDim.x;
    for (int i = blockIdx.x * blockDim.x + threadIdx.x; i < NTX + NT13 + NT2; i += stride) {
        float4 v;
        ushort4* dst;
        if (i < NTX) {
            int row = i >> 8;            // D/4 = 256 chunks per row
            int c4  = i & 255;
            v = reinterpret_cast<const float4*>(X)[i];
            float sc = S[row * (DDIM / 32) + (c4 >> 3)];
            v.x *= sc; v.y *= sc; v.z *= sc; v.w *= sc;
            dst = (ushort4*)Xb + i;
        } else if (i < NTX + NT13) {
            int j = i - NTX;
            v = reinterpret_cast<const float4*>(W13)[j];
            dst = (ushort4*)W13b + j;
        } else {
            int j = i - NTX - NT13;
            v = reinterpret_cast<const float4*>(W2)[j];
            dst = (ushort4*)W2b + j;
        }
        ushort4 b;
        b.x = f2bf(v.x); b.y = f2bf(v.y); b.z = f2bf(v.z); b.w = f2bf(v.w);
        *dst = b;
    }
}

// XCD-aware swizzle for 512-block grids (512 % 8 == 0 -> bijective):
// each XCD gets a contiguous chunk of 64 logical blocks (= one expert).
__device__ __forceinline__ int xcd_swizzle_512(int raw) {
    return (raw & 7) * 64 + (raw >> 3);
}

// ---------------------------------------------------------------------------
// Kernel 1: h = silu(Xb W1^T) * (Xb W3^T). Pure bf16, gld_lds both operands.
// Tile: M=128 tokens x 64 h-cols (paired w1+w3 => 128 B rows), BK=64.
// sB rows [0,64) = w1 rows [nt*64,+64); rows [64,128) = w3 rows [H+nt*64,+64).
// 4 waves 2x2; per-wave 64x32 per set. grid = 512, LDS 32 KB.
// ---------------------------------------------------------------------------
__global__ __launch_bounds__(256, 2)
void gemm1_silu_kernel(const unsigned short* __restrict__ Xb,
                       const unsigned short* __restrict__ W13b,
                       __hip_bfloat16* __restrict__ Hout)
{
    const int bid = xcd_swizzle_512(blockIdx.x);
    const int e  = bid >> 6;
    const int mt = (bid >> 3) & 7;    // token tile (128 rows)
    const int nt = bid & 7;           // h tile (64 cols)
    const int tok0 = e * TPE + mt * 128;
    const unsigned short* __restrict__ We = W13b + (size_t)e * (2 * HDIM) * DDIM;

    __shared__ __hip_bfloat16 sA[128][64];
    __shared__ __hip_bfloat16 sB[128][64];

    const int tid  = threadIdx.x;
    const int lane = tid & 63;
    const int wave = tid >> 6;
    const int wr = wave >> 1;   // 0..1 (M half)
    const int wc = wave & 1;    // 0..1 (N: 32 cols each)
    const int lr = lane & 15;
    const int lk = (lane >> 4) * 8;

    floatx4 acc1[4][2] = {};
    floatx4 acc3[4][2] = {};

    // staging geometry: chunk c in [0,1024): row = c>>3, col = (c&7)*8
    const int srow0 = (tid >> 3);     // 0..31
    const int scol  = (tid & 7) * 8;

    for (int kk = 0; kk < DDIM / 64; ++kk) {
        const int k0 = kk * 64;
        #pragma unroll
        for (int j = 0; j < 4; ++j) {
            int row = srow0 + j * 32;
            gld_lds16(&Xb[(size_t)(tok0 + row) * DDIM + k0 + scol],
                      &sA[row][scol]);
            int wrow = (j < 2) ? (nt * 64 + row)                    // w1 rows
                               : (HDIM + nt * 64 + (row - 64));     // w3 rows
            gld_lds16(&We[(size_t)wrow * DDIM + k0 + scol],
                      &sB[row][scol]);
        }
        __syncthreads();
        #pragma unroll
        for (int ks = 0; ks < 2; ++ks) {
            bf16x8 a[4], b1[2], b3[2];
            #pragma unroll
            for (int m = 0; m < 4; ++m)
                a[m] = *reinterpret_cast<const bf16x8*>(&sA[wr * 64 + m * 16 + lr][ks * 32 + lk]);
            #pragma unroll
            for (int n = 0; n < 2; ++n) {
                b1[n] = *reinterpret_cast<const bf16x8*>(&sB[wc * 32 + n * 16 + lr][ks * 32 + lk]);
                b3[n] = *reinterpret_cast<const bf16x8*>(&sB[64 + wc * 32 + n * 16 + lr][ks * 32 + lk]);
            }
            #pragma unroll
            for (int m = 0; m < 4; ++m)
                #pragma unroll
                for (int n = 0; n < 2; ++n) {
                    acc1[m][n] = __builtin_amdgcn_mfma_f32_16x16x32_bf16(a[m], b1[n], acc1[m][n], 0, 0, 0);
                    acc3[m][n] = __builtin_amdgcn_mfma_f32_16x16x32_bf16(a[m], b3[n], acc3[m][n], 0, 0, 0);
                }
        }
        __syncthreads();
    }

    // ---- epilogue: h = silu(h1) * h3 -> bf16
    const int hcol0 = nt * 64 + wc * 32;
    #pragma unroll
    for (int m = 0; m < 4; ++m) {
        #pragma unroll
        for (int n = 0; n < 2; ++n) {
            #pragma unroll
            for (int i = 0; i < 4; ++i) {
                int row = tok0 + wr * 64 + m * 16 + (lane >> 4) * 4 + i;
                int col = hcol0 + n * 16 + (lane & 15);
                float h1 = acc1[m][n][i];
                float h3 = acc3[m][n][i];
                float sig = 1.0f / (1.0f + __expf(-h1));
                Hout[(size_t)row * HDIM + col] = __float2bfloat16(h1 * sig * h3);
            }
        }
    }
}

// ---------------------------------------------------------------------------
// Kernel 2: out = h W2^T. All-bf16, gld_lds both operands.
// Tile 128x128, BK=64, K=512. grid = 512.
// ---------------------------------------------------------------------------
__global__ __launch_bounds__(256, 2)
void gemm2_kernel(const __hip_bfloat16* __restrict__ Hin,
                  const unsigned short* __restrict__ W2b,
                  float* __restrict__ Out)
{
    const int bid = xcd_swizzle_512(blockIdx.x);
    const int e  = bid >> 6;
    const int mt = (bid >> 3) & 7;
    const int nt = bid & 7;
    const int tok0 = e * TPE + mt * 128;
    const unsigned short* __restrict__ We = W2b + (size_t)e * DDIM * HDIM;

    __shared__ __hip_bfloat16 sA[128][64];
    __shared__ __hip_bfloat16 sB[128][64];

    const int tid  = threadIdx.x;
    const int lane = tid & 63;
    const int wave = tid >> 6;
    const int wr = wave >> 1;
    const int wc = wave & 1;
    const int lr = lane & 15;
    const int lk = (lane >> 4) * 8;

    floatx4 acc[4][4] = {};

    const int srow0 = (tid >> 3);
    const int scol  = (tid & 7) * 8;

    for (int kk = 0; kk < HDIM / 64; ++kk) {
        const int k0 = kk * 64;
        #pragma unroll
        for (int j = 0; j < 4; ++j) {
            int row = srow0 + j * 32;
            gld_lds16(&Hin[(size_t)(tok0 + row) * HDIM + k0 + scol],
                      &sA[row][scol]);
            gld_lds16(&We[(size_t)(nt * 128 + row) * HDIM + k0 + scol],
                      &sB[row][scol]);
        }
        __syncthreads();
        #pragma unroll
        for (int ks = 0; ks < 2; ++ks) {
            bf16x8 a[4], b[4];
            #pragma unroll
            for (int m = 0; m < 4; ++m)
                a[m] = *reinterpret_cast<const bf16x8*>(&sA[wr * 64 + m * 16 + lr][ks * 32 + lk]);
            #pragma unroll
            for (int n = 0; n < 4; ++n)
                b[n] = *reinterpret_cast<const bf16x8*>(&sB[wc * 64 + n * 16 + lr][ks * 32 + lk]);
            #pragma unroll
            for (int m = 0; m < 4; ++m)
                #pragma unroll
                for (int n = 0; n < 4; ++n)
                    acc[m][n] = __builtin_amdgcn_mfma_f32_16x16x32_bf16(a[m], b[n], acc[m][n], 0, 0, 0);
        }
        __syncthreads();
    }

    const int dcol0 = nt * 128 + wc * 64;
    #pragma unroll
    for (int m = 0; m < 4; ++m) {
        #pragma unroll
        for (int n = 0; n < 4; ++n) {
            #pragma unroll
            for (int i = 0; i < 4; ++i) {
                int row = tok0 + wr * 64 + m * 16 + (lane >> 4) * 4 + i;
                int col = dcol0 + n * 16 + (lane & 15);
                Out[(size_t)row * DDIM + col] = acc[m][n][i];
            }
        }
    }
}

extern "C" void kernel_launch(void* const* d_in, const int* in_sizes, int n_in,
                              void* d_out, int out_size, void* d_ws, size_t ws_size,
                              hipStream_t stream) {
    const float* X   = (const float*)d_in[0];   // (T, D) fp32
    const float* S   = (const float*)d_in[1];   // (T, D/32) fp32
    const float* W13 = (const float*)d_in[4];   // (E, 2H, D) fp32
    const float* W2  = (const float*)d_in[5];   // (E, D, H) fp32
    float* Out = (float*)d_out;                 // (T, D) fp32

    // workspace layout (bytes):
    //   [0, 16Mi)    W13b bf16 (E*2H*D)
    //   [16Mi, 24Mi) W2b  bf16 (E*D*H)
    //   [24Mi, 32Mi) Hb   bf16 (T*H)
    // Xb (T*D bf16 = 16 MiB) lives in d_out's first half: gemm1 consumes it,
    // then gemm2 overwrites all of d_out with the final fp32 output.
    unsigned short* W13b = (unsigned short*)d_ws;
    unsigned short* W2b  = W13b + (size_t)NE * 2 * HDIM * DDIM;
    __hip_bfloat16* Hb   = (__hip_bfloat16*)(W2b + (size_t)NE * DDIM * HDIM);
    unsigned short* Xb   = (unsigned short*)d_out;

    convert_kernel<<<2048, 256, 0, stream>>>(X, S, W13, W2, Xb, W13b, W2b);
    gemm1_silu_kernel<<<NE * 8 * 8, 256, 0, stream>>>(Xb, W13b, Hb);
    gemm2_kernel<<<NE * 8 * 8, 256, 0, stream>>>(Hb, W2b, Out);
}

// Round 4
// 65.546 us; speedup vs baseline: 3.0963x; 1.0548x over previous
//
#include <hip/hip_runtime.h>
#include <hip/hip_bf16.h>

// Problem constants (match reference)
#define T_TOK 8192
#define DDIM  1024
#define HDIM  512
#define NE    8
#define TPE   (T_TOK / NE)   // 1024 tokens per expert (static partition per reference)

typedef __attribute__((ext_vector_type(4))) float floatx4;
typedef __attribute__((ext_vector_type(8))) short bf16x8;

__device__ __forceinline__ unsigned short f2bf(float f) {
    union { float f; unsigned int u; } v;
    v.f = f;
    unsigned int u = v.u;
    unsigned int r = u + 0x7FFFu + ((u >> 16) & 1u);  // RNE
    return (unsigned short)(r >> 16);
}

// async global -> LDS, 16 bytes per lane (dest must be linear: base + lane*16)
__device__ __forceinline__ void gld_lds16(const void* g, void* l) {
    __builtin_amdgcn_global_load_lds(
        (const __attribute__((address_space(1))) unsigned int*)g,
        (__attribute__((address_space(3))) unsigned int*)l, 16, 0, 0);
}

// ---------------------------------------------------------------------------
// Kernel 0 (streaming): W13 fp32->bf16, W2 fp32->bf16, X*scale -> bf16.
// ---------------------------------------------------------------------------
__global__ __launch_bounds__(256)
void convert_kernel(const float* __restrict__ X, const float* __restrict__ S,
                    const float* __restrict__ W13, const float* __restrict__ W2,
                    unsigned short* __restrict__ Xb,
                    unsigned short* __restrict__ W13b,
                    unsigned short* __restrict__ W2b)
{
    const int NTX  = (T_TOK * DDIM) / 4;           // 2,097,152 float4 chunks
    const int NT13 = (NE * 2 * HDIM * DDIM) / 4;   // 2,097,152
    const int NT2  = (NE * DDIM * HDIM) / 4;       // 1,048,576
    const int stride = gridDim.x * blockDim.x;
    for (int i = blockIdx.x * blockDim.x + threadIdx.x; i < NTX + NT13 + NT2; i += stride) {
        float4 v;
        ushort4* dst;
        if (i < NTX) {
            int row = i >> 8;            // D/4 = 256 chunks per row
            int c4  = i & 255;
            v = reinterpret_cast<const float4*>(X)[i];
            float sc = S[row * (DDIM / 32) + (c4 >> 3)];
            v.x *= sc; v.y *= sc; v.z *= sc; v.w *= sc;
            dst = (ushort4*)Xb + i;
        } else if (i < NTX + NT13) {
            int j = i - NTX;
            v = reinterpret_cast<const float4*>(W13)[j];
            dst = (ushort4*)W13b + j;
        } else {
            int j = i - NTX - NT13;
            v = reinterpret_cast<const float4*>(W2)[j];
            dst = (ushort4*)W2b + j;
        }
        ushort4 b;
        b.x = f2bf(v.x); b.y = f2bf(v.y); b.z = f2bf(v.z); b.w = f2bf(v.w);
        *dst = b;
    }
}

// XCD-aware swizzle for 512-block grids (512 % 8 == 0 -> bijective):
// each XCD gets a contiguous chunk of 64 logical blocks (= one expert).
__device__ __forceinline__ int xcd_swizzle_512(int raw) {
    return (raw & 7) * 64 + (raw >> 3);
}

// ---------------------------------------------------------------------------
// Kernel 1: h = silu(Xb W1^T) * (Xb W3^T). Pure bf16, gld_lds both operands.
// Tile: M=128 tokens x 64 h-cols (paired w1+w3 => 128 B rows), BK=64, K=1024.
// Double-buffered LDS + prefetch-next-tile + counted vmcnt (min-2-phase T3/T4):
// loads for tile t+1 stay in flight while computing tile t; barriers are raw
// s_barrier (no vmcnt(0) drain in the main loop).
// 4 waves 2x2; grid = 512, LDS 64 KB -> 2 blocks/CU.
// ---------------------------------------------------------------------------
__global__ __launch_bounds__(256, 2)
void gemm1_silu_kernel(const unsigned short* __restrict__ Xb,
                       const unsigned short* __restrict__ W13b,
                       __hip_bfloat16* __restrict__ Hout)
{
    const int bid = xcd_swizzle_512(blockIdx.x);
    const int e  = bid >> 6;
    const int mt = (bid >> 3) & 7;    // token tile (128 rows)
    const int nt = bid & 7;           // h tile (64 cols)
    const int tok0 = e * TPE + mt * 128;
    const unsigned short* __restrict__ We = W13b + (size_t)e * (2 * HDIM) * DDIM;

    __shared__ __hip_bfloat16 sA[2][128][64];
    __shared__ __hip_bfloat16 sB[2][128][64];

    const int tid  = threadIdx.x;
    const int lane = tid & 63;
    const int wave = tid >> 6;
    const int wr = wave >> 1;   // 0..1 (M half)
    const int wc = wave & 1;    // 0..1 (N: 32 cols each)
    const int lr = lane & 15;
    const int lk = (lane >> 4) * 8;

    floatx4 acc1[4][2] = {};
    floatx4 acc3[4][2] = {};

    // staging geometry: chunk c in [0,1024): row = c>>3, col = (c&7)*8
    const int srow0 = (tid >> 3);     // 0..31
    const int scol  = (tid & 7) * 8;

    // 8 gld_lds per thread per tile
    auto STAGE = [&](int kk, int buf) {
        const int k0 = kk * 64;
        #pragma unroll
        for (int j = 0; j < 4; ++j) {
            int row = srow0 + j * 32;
            gld_lds16(&Xb[(size_t)(tok0 + row) * DDIM + k0 + scol],
                      &sA[buf][row][scol]);
            int wrow = (j < 2) ? (nt * 64 + row)                    // w1 rows
                               : (HDIM + nt * 64 + (row - 64));     // w3 rows
            gld_lds16(&We[(size_t)wrow * DDIM + k0 + scol],
                      &sB[buf][row][scol]);
        }
    };
    auto COMPUTE = [&](int buf) {
        #pragma unroll
        for (int ks = 0; ks < 2; ++ks) {
            bf16x8 a[4], b1[2], b3[2];
            #pragma unroll
            for (int m = 0; m < 4; ++m)
                a[m] = *reinterpret_cast<const bf16x8*>(&sA[buf][wr * 64 + m * 16 + lr][ks * 32 + lk]);
            #pragma unroll
            for (int n = 0; n < 2; ++n) {
                b1[n] = *reinterpret_cast<const bf16x8*>(&sB[buf][wc * 32 + n * 16 + lr][ks * 32 + lk]);
                b3[n] = *reinterpret_cast<const bf16x8*>(&sB[buf][64 + wc * 32 + n * 16 + lr][ks * 32 + lk]);
            }
            #pragma unroll
            for (int m = 0; m < 4; ++m)
                #pragma unroll
                for (int n = 0; n < 2; ++n) {
                    acc1[m][n] = __builtin_amdgcn_mfma_f32_16x16x32_bf16(a[m], b1[n], acc1[m][n], 0, 0, 0);
                    acc3[m][n] = __builtin_amdgcn_mfma_f32_16x16x32_bf16(a[m], b3[n], acc3[m][n], 0, 0, 0);
                }
        }
    };

    STAGE(0, 0);
    for (int kk = 0; kk < DDIM / 64 - 1; ++kk) {       // kk = 0..14
        STAGE(kk + 1, (kk + 1) & 1);
        asm volatile("s_waitcnt vmcnt(8)" ::: "memory");  // current tile landed
        __builtin_amdgcn_sched_barrier(0);
        __builtin_amdgcn_s_barrier();
        COMPUTE(kk & 1);
        __builtin_amdgcn_s_barrier();                  // guard buf before next STAGE
    }
    asm volatile("s_waitcnt vmcnt(0)" ::: "memory");
    __builtin_amdgcn_sched_barrier(0);
    __builtin_amdgcn_s_barrier();
    COMPUTE(1);                                        // tile 15

    // ---- epilogue: h = silu(h1) * h3 -> bf16
    const int hcol0 = nt * 64 + wc * 32;
    #pragma unroll
    for (int m = 0; m < 4; ++m) {
        #pragma unroll
        for (int n = 0; n < 2; ++n) {
            #pragma unroll
            for (int i = 0; i < 4; ++i) {
                int row = tok0 + wr * 64 + m * 16 + (lane >> 4) * 4 + i;
                int col = hcol0 + n * 16 + (lane & 15);
                float h1 = acc1[m][n][i];
                float h3 = acc3[m][n][i];
                float sig = 1.0f / (1.0f + __expf(-h1));
                Hout[(size_t)row * HDIM + col] = __float2bfloat16(h1 * sig * h3);
            }
        }
    }
}

// ---------------------------------------------------------------------------
// Kernel 2: out = h W2^T. All-bf16, gld_lds, same prefetch-2ph structure.
// Tile 128x128, BK=64, K=512 (8 K-steps). grid = 512, LDS 64 KB.
// ---------------------------------------------------------------------------
__global__ __launch_bounds__(256, 2)
void gemm2_kernel(const __hip_bfloat16* __restrict__ Hin,
                  const unsigned short* __restrict__ W2b,
                  float* __restrict__ Out)
{
    const int bid = xcd_swizzle_512(blockIdx.x);
    const int e  = bid >> 6;
    const int mt = (bid >> 3) & 7;
    const int nt = bid & 7;
    const int tok0 = e * TPE + mt * 128;
    const unsigned short* __restrict__ We = W2b + (size_t)e * DDIM * HDIM;

    __shared__ __hip_bfloat16 sA[2][128][64];
    __shared__ __hip_bfloat16 sB[2][128][64];

    const int tid  = threadIdx.x;
    const int lane = tid & 63;
    const int wave = tid >> 6;
    const int wr = wave >> 1;
    const int wc = wave & 1;
    const int lr = lane & 15;
    const int lk = (lane >> 4) * 8;

    floatx4 acc[4][4] = {};

    const int srow0 = (tid >> 3);
    const int scol  = (tid & 7) * 8;

    auto STAGE = [&](int kk, int buf) {
        const int k0 = kk * 64;
        #pragma unroll
        for (int j = 0; j < 4; ++j) {
            int row = srow0 + j * 32;
            gld_lds16(&Hin[(size_t)(tok0 + row) * HDIM + k0 + scol],
                      &sA[buf][row][scol]);
            gld_lds16(&We[(size_t)(nt * 128 + row) * HDIM + k0 + scol],
                      &sB[buf][row][scol]);
        }
    };
    auto COMPUTE = [&](int buf) {
        #pragma unroll
        for (int ks = 0; ks < 2; ++ks) {
            bf16x8 a[4], b[4];
            #pragma unroll
            for (int m = 0; m < 4; ++m)
                a[m] = *reinterpret_cast<const bf16x8*>(&sA[buf][wr * 64 + m * 16 + lr][ks * 32 + lk]);
            #pragma unroll
            for (int n = 0; n < 4; ++n)
                b[n] = *reinterpret_cast<const bf16x8*>(&sB[buf][wc * 64 + n * 16 + lr][ks * 32 + lk]);
            #pragma unroll
            for (int m = 0; m < 4; ++m)
                #pragma unroll
                for (int n = 0; n < 4; ++n)
                    acc[m][n] = __builtin_amdgcn_mfma_f32_16x16x32_bf16(a[m], b[n], acc[m][n], 0, 0, 0);
        }
    };

    STAGE(0, 0);
    for (int kk = 0; kk < HDIM / 64 - 1; ++kk) {       // kk = 0..6
        STAGE(kk + 1, (kk + 1) & 1);
        asm volatile("s_waitcnt vmcnt(8)" ::: "memory");
        __builtin_amdgcn_sched_barrier(0);
        __builtin_amdgcn_s_barrier();
        COMPUTE(kk & 1);
        __builtin_amdgcn_s_barrier();
    }
    asm volatile("s_waitcnt vmcnt(0)" ::: "memory");
    __builtin_amdgcn_sched_barrier(0);
    __builtin_amdgcn_s_barrier();
    COMPUTE(1);                                        // tile 7

    const int dcol0 = nt * 128 + wc * 64;
    #pragma unroll
    for (int m = 0; m < 4; ++m) {
        #pragma unroll
        for (int n = 0; n < 4; ++n) {
            #pragma unroll
            for (int i = 0; i < 4; ++i) {
                int row = tok0 + wr * 64 + m * 16 + (lane >> 4) * 4 + i;
                int col = dcol0 + n * 16 + (lane & 15);
                Out[(size_t)row * DDIM + col] = acc[m][n][i];
            }
        }
    }
}

extern "C" void kernel_launch(void* const* d_in, const int* in_sizes, int n_in,
                              void* d_out, int out_size, void* d_ws, size_t ws_size,
                              hipStream_t stream) {
    const float* X   = (const float*)d_in[0];   // (T, D) fp32
    const float* S   = (const float*)d_in[1];   // (T, D/32) fp32
    const float* W13 = (const float*)d_in[4];   // (E, 2H, D) fp32
    const float* W2  = (const float*)d_in[5];   // (E, D, H) fp32
    float* Out = (float*)d_out;                 // (T, D) fp32

    // workspace layout (bytes):
    //   [0, 16Mi)    W13b bf16 (E*2H*D)
    //   [16Mi, 24Mi) W2b  bf16 (E*D*H)
    //   [24Mi, 32Mi) Hb   bf16 (T*H)
    // Xb (T*D bf16 = 16 MiB) lives in d_out's first half: gemm1 consumes it,
    // then gemm2 overwrites all of d_out with the final fp32 output.
    unsigned short* W13b = (unsigned short*)d_ws;
    unsigned short* W2b  = W13b + (size_t)NE * 2 * HDIM * DDIM;
    __hip_bfloat16* Hb   = (__hip_bfloat16*)(W2b + (size_t)NE * DDIM * HDIM);
    unsigned short* Xb   = (unsigned short*)d_out;

    convert_kernel<<<2048, 256, 0, stream>>>(X, S, W13, W2, Xb, W13b, W2b);
    gemm1_silu_kernel<<<NE * 8 * 8, 256, 0, stream>>>(Xb, W13b, Hb);
    gemm2_kernel<<<NE * 8 * 8, 256, 0, stream>>>(Hb, W2b, Out);
}